// Round 3
// baseline (334.423 us; speedup 1.0000x reference)
//
#include <hip/hip_runtime.h>
#include <math.h>

// ---------------------------------------------------------------------------
// Chamfer distance via MFMA (gfx950) — round 3: occupancy + epilogue trim.
//
// d2(p,g) = p^2 + g^2 - 2 p.g computed entirely inside
// v_mfma_f32_32x32x16_bf16 via bf16 hi/lo (Dekker) split over K=16 slots
// (HW-verified absmax 0.0 in rounds 1-2).
//
// Round 2 was latency-bound: 4 blocks/CU, VALUBusy 20%, Occupancy 24%.
// This round: 2048 blocks (8/CU -> 32 waves/CU at <=64 VGPR), plus cheaper
// reductions (no per-step cross-half shfl; 4-stage row butterfly + cndmask
// select tree + single full-exec atomic, relying on atomicMin to merge).
// ---------------------------------------------------------------------------

constexpr int NPTS  = 16384;
constexpr int BLOCK = 256;                        // 4 waves
constexpr int WAVES = BLOCK / 64;

constexpr int ROWS_PER_BLOCK = 256;
constexpr int COLS_PER_BLOCK = 512;
constexpr int NBX = NPTS / ROWS_PER_BLOCK;        // 64
constexpr int NBY = NPTS / COLS_PER_BLOCK;        // 32
constexpr int NBLOCKS = NBX * NBY;                // 2048
constexpr int ROWS_PER_WAVE = ROWS_PER_BLOCK / WAVES;   // 64
constexpr int ATILES = ROWS_PER_WAVE / 32;        // 2
constexpr int CSTEPS = COLS_PER_BLOCK / 64;       // 8 (two 32-col tiles/step)

typedef __attribute__((ext_vector_type(8)))  __bf16 bf16x8;
typedef __attribute__((ext_vector_type(16))) float  f32x16;

__device__ inline unsigned short f2bf(float f) {          // RNE float->bf16
    unsigned u = __float_as_uint(f);
    u += 0x7FFFu + ((u >> 16) & 1u);
    return (unsigned short)(u >> 16);
}
__device__ inline float bf2f(unsigned short h) {
    return __uint_as_float(((unsigned)h) << 16);
}
__device__ inline unsigned pk(unsigned short lo, unsigned short hi) {
    return (unsigned)lo | ((unsigned)hi << 16);
}

// ---------------------------------------------------------------------------
// Pack to FRAG-READY layout: per point two uint4s (one per k-half), each the
// exact 8-bf16 MFMA fragment for that half (verified layout, rounds 1-2):
//   A half0: [phx,phy,phz, plx,ply,plz, phx,phy]
//   A half1: [phz, p2h, p2l, 1, 1, plx, ply, plz]
//   B half0: [mhx,mhy,mhz, mhx,mhy,mhz, mlx,mly]      (m = -2g)
//   B half1: [mlz, 1, 1, g2h, g2l, mlx, mly, mlz]
// Array layout: half-major — Xf[half*NPTS + i].
// ---------------------------------------------------------------------------
__global__ __launch_bounds__(BLOCK) void pack_init_kernel(
    const float* __restrict__ pred, const float* __restrict__ gt,
    uint4* __restrict__ Af, uint4* __restrict__ Bf,
    unsigned int* __restrict__ minP, unsigned int* __restrict__ minG,
    unsigned int* __restrict__ ticket)
{
    const unsigned short ONE = 0x3F80;
    int i = blockIdx.x * BLOCK + threadIdx.x;
    if (i == 0) *ticket = 0u;
    if (i >= NPTS) return;

    {   // A side (pred)
        float x = pred[3*i], y = pred[3*i+1], z = pred[3*i+2];
        unsigned short hx = f2bf(x), hy = f2bf(y), hz = f2bf(z);
        unsigned short lx = f2bf(x - bf2f(hx));
        unsigned short ly = f2bf(y - bf2f(hy));
        unsigned short lz = f2bf(z - bf2f(hz));
        float p2 = fmaf(x, x, fmaf(y, y, z * z));
        unsigned short sh = f2bf(p2), sl = f2bf(p2 - bf2f(sh));
        uint4 h0, h1;
        h0.x = pk(hx, hy); h0.y = pk(hz, lx); h0.z = pk(ly, lz); h0.w = pk(hx, hy);
        h1.x = pk(hz, sh); h1.y = pk(sl, ONE); h1.z = pk(ONE, lx); h1.w = pk(ly, lz);
        Af[i] = h0;
        Af[NPTS + i] = h1;
    }
    {   // B side (gt, pre-scaled by -2)
        float gx = gt[3*i], gy = gt[3*i+1], gz = gt[3*i+2];
        float mx = -2.0f * gx, my = -2.0f * gy, mz = -2.0f * gz;
        unsigned short hx = f2bf(mx), hy = f2bf(my), hz = f2bf(mz);
        unsigned short lx = f2bf(mx - bf2f(hx));
        unsigned short ly = f2bf(my - bf2f(hy));
        unsigned short lz = f2bf(mz - bf2f(hz));
        float g2 = fmaf(gx, gx, fmaf(gy, gy, gz * gz));
        unsigned short sh = f2bf(g2), sl = f2bf(g2 - bf2f(sh));
        uint4 h0, h1;
        h0.x = pk(hx, hy); h0.y = pk(hz, hx); h0.z = pk(hy, hz); h0.w = pk(lx, ly);
        h1.x = pk(lz, ONE); h1.y = pk(ONE, sh); h1.z = pk(sl, lx); h1.w = pk(ly, lz);
        Bf[i] = h0;
        Bf[NPTS + i] = h1;
    }
    minP[i] = 0x7F800000u;   // +inf
    minG[i] = 0x7F800000u;
}

__device__ inline float tree16(const f32x16 a) {   // min of 16 (v_min3 tree)
    float m0 = fminf(fminf(a[0],  a[1]),  a[2]);
    float m1 = fminf(fminf(a[3],  a[4]),  a[5]);
    float m2 = fminf(fminf(a[6],  a[7]),  a[8]);
    float m3 = fminf(fminf(a[9],  a[10]), a[11]);
    float m4 = fminf(fminf(a[12], a[13]), a[14]);
    float m5 = fminf(fminf(m0, m1), m2);
    float m6 = fminf(fminf(m3, m4), a[15]);
    return fminf(m5, m6);
}

// ---------------------------------------------------------------------------
// Main kernel: grid (64,32); block tile 256 rows x 512 cols, 4 waves.
// Wave w owns rows [w*64, w*64+64), one 32-row A-tile at a time.
// C/D layout (HW-verified): col = lane&31, row = (reg&3)+8*(reg>>2)+4*(lane>>5).
// ---------------------------------------------------------------------------
__global__ __launch_bounds__(BLOCK, 8) void chamfer_mfma_kernel(
    const uint4* __restrict__ Af, const uint4* __restrict__ Bf,
    unsigned int* __restrict__ minP, unsigned int* __restrict__ minG,
    const float* __restrict__ wpred, const float* __restrict__ wgt,
    unsigned int* __restrict__ ticket, float* __restrict__ out)
{
    const int tid  = threadIdx.x;
    const int wv   = tid >> 6;
    const int lane = tid & 63;
    const int half = lane >> 5;
    const int ln31 = lane & 31;

    const int rowBase = blockIdx.x * ROWS_PER_BLOCK + wv * ROWS_PER_WAVE;
    const int colBase = blockIdx.y * COLS_PER_BLOCK;

    __shared__ unsigned int cminS[COLS_PER_BLOCK];
    for (int c = tid; c < COLS_PER_BLOCK; c += BLOCK)
        cminS[c] = 0x7F800000u;
    __syncthreads();

    // Per-half base pointers; a fragment is exactly one uint4.
    const uint4* __restrict__ Ah = Af + half * NPTS;
    const uint4* __restrict__ Bh = Bf + half * NPTS + colBase;

    const f32x16 zacc = {0.f,0.f,0.f,0.f, 0.f,0.f,0.f,0.f,
                         0.f,0.f,0.f,0.f, 0.f,0.f,0.f,0.f};

    #pragma unroll 1
    for (int a = 0; a < ATILES; ++a) {
        uint4 ac = Ah[rowBase + a * 32 + ln31];
        bf16x8 af = __builtin_bit_cast(bf16x8, ac);

        float rm[16];
        #pragma unroll
        for (int r = 0; r < 16; ++r) rm[r] = INFINITY;

        #pragma unroll 2
        for (int s = 0; s < CSTEPS; ++s) {
            bf16x8 b0 = __builtin_bit_cast(bf16x8, Bh[s * 64 + ln31]);
            bf16x8 b1 = __builtin_bit_cast(bf16x8, Bh[s * 64 + 32 + ln31]);
            f32x16 acc0 = __builtin_amdgcn_mfma_f32_32x32x16_bf16(af, b0, zacc, 0, 0, 0);
            f32x16 acc1 = __builtin_amdgcn_mfma_f32_32x32x16_bf16(af, b1, zacc, 0, 0, 0);
            #pragma unroll
            for (int r = 0; r < 16; ++r)
                rm[r] = fminf(rm[r], fminf(acc0[r], acc1[r]));   // v_min3
            // Col mins: both halves atomic their own partial (merge in LDS).
            float c0 = fmaxf(tree16(acc0), 0.0f);
            float c1 = fmaxf(tree16(acc1), 0.0f);
            atomicMin(&cminS[s * 64 + ln31],      __float_as_uint(c0));
            atomicMin(&cminS[s * 64 + 32 + ln31], __float_as_uint(c1));
        }

        // Row mins: 4-stage butterfly over 16-lane groups; the two groups
        // (cols 0-15 / 16-31) write the same minP slot -> atomicMin merges.
        #pragma unroll
        for (int s = 1; s < 16; s <<= 1) {
            #pragma unroll
            for (int r = 0; r < 16; ++r)
                rm[r] = fminf(rm[r], __shfl_xor(rm[r], s, 64));
        }
        // Lane q=ln31&15 selects rm[q] via cndmask tree (no runtime indexing).
        const int q  = ln31 & 15;
        const bool b3 = (q & 8) != 0, b2 = (q & 4) != 0,
                   b1 = (q & 2) != 0, b0 = (q & 1) != 0;
        float s0 = b3 ? rm[8]  : rm[0];
        float s1 = b3 ? rm[9]  : rm[1];
        float s2 = b3 ? rm[10] : rm[2];
        float s3 = b3 ? rm[11] : rm[3];
        float s4 = b3 ? rm[12] : rm[4];
        float s5 = b3 ? rm[13] : rm[5];
        float s6 = b3 ? rm[14] : rm[6];
        float s7 = b3 ? rm[15] : rm[7];
        float t0 = b2 ? s4 : s0;
        float t1 = b2 ? s5 : s1;
        float t2 = b2 ? s6 : s2;
        float t3 = b2 ? s7 : s3;
        float u0 = b1 ? t2 : t0;
        float u1 = b1 ? t3 : t1;
        float v  = b0 ? u1 : u0;
        const int rb = rowBase + a * 32 + 4 * half;
        atomicMin(&minP[rb + (q & 3) + 8 * (q >> 2)],
                  __float_as_uint(fmaxf(v, 0.0f)));
    }

    __syncthreads();
    for (int c = tid; c < COLS_PER_BLOCK; c += BLOCK)
        atomicMin(&minG[colBase + c], cminS[c]);   // already clamped >= 0

    // ------------------- ticket: last block finalizes -----------------------
    __shared__ unsigned int sTicket;
    __syncthreads();
    __threadfence();
    if (tid == 0) sTicket = atomicAdd(ticket, 1u);
    __syncthreads();
    if (sTicket != (unsigned)(NBLOCKS - 1)) return;
    __threadfence();

    // Read via identity atomics (coherent across XCDs), weighted sums.
    float np = 0.f, dp = 0.f, ng = 0.f, dg = 0.f;
    for (int i = tid; i < NPTS; i += BLOCK) {
        float v = __uint_as_float(atomicMin(&minP[i], 0xFFFFFFFFu));
        float w = wpred[i];
        np = fmaf(w, v, np); dp += w;
        float u = __uint_as_float(atomicMin(&minG[i], 0xFFFFFFFFu));
        float x = wgt[i];
        ng = fmaf(x, u, ng); dg += x;
    }
    #pragma unroll
    for (int off = 1; off < 64; off <<= 1) {
        np += __shfl_xor(np, off, 64);
        dp += __shfl_xor(dp, off, 64);
        ng += __shfl_xor(ng, off, 64);
        dg += __shfl_xor(dg, off, 64);
    }
    __shared__ float sred[4][WAVES];
    if (lane == 0) { sred[0][wv] = np; sred[1][wv] = dp;
                     sred[2][wv] = ng; sred[3][wv] = dg; }
    __syncthreads();
    if (tid == 0) {
        float NP = 0.f, DP = 0.f, NG = 0.f, DG = 0.f;
        #pragma unroll
        for (int k = 0; k < WAVES; ++k) {
            NP += sred[0][k]; DP += sred[1][k];
            NG += sred[2][k]; DG += sred[3][k];
        }
        out[0] = NP / fmaxf(DP, 1e-9f) + NG / fmaxf(DG, 1e-9f);
    }
}

// ---------------------------------------------------------------------------
extern "C" void kernel_launch(void* const* d_in, const int* in_sizes, int n_in,
                              void* d_out, int out_size, void* d_ws, size_t ws_size,
                              hipStream_t stream)
{
    const float* pred  = (const float*)d_in[0];   // (P,3)
    const float* gt    = (const float*)d_in[1];   // (G,3)
    const float* wpred = (const float*)d_in[2];   // (P,)
    const float* wgt   = (const float*)d_in[3];   // (G,)
    float* out = (float*)d_out;

    // ws: Af(512K) | Bf(512K) | minP(64K) | minG(64K) | ticket  (~1.13 MB)
    uint4* Af = (uint4*)d_ws;
    uint4* Bf = Af + 2 * NPTS;
    unsigned int* minP = (unsigned int*)(Bf + 2 * NPTS);
    unsigned int* minG = minP + NPTS;
    unsigned int* ticket = minG + NPTS;

    pack_init_kernel<<<NPTS / BLOCK, BLOCK, 0, stream>>>(
        pred, gt, Af, Bf, minP, minG, ticket);

    chamfer_mfma_kernel<<<dim3(NBX, NBY), BLOCK, 0, stream>>>(
        Af, Bf, minP, minG, wpred, wgt, ticket, out);
}

// Round 4
// 268.185 us; speedup vs baseline: 1.2470x; 1.2470x over previous
//
#include <hip/hip_runtime.h>
#include <math.h>

// ---------------------------------------------------------------------------
// Chamfer distance via MFMA (gfx950) — round 4.
//
// d2(p,g) = p^2 + g^2 - 2 p.g computed entirely inside
// v_mfma_f32_32x32x16_bf16 via bf16 hi/lo (Dekker) split over K=16 slots
// (HW-verified absmax 0.0, rounds 1-3).
//
// Round 2: correct + spill-free but latency-bound (4 blocks/CU, VALUBusy 20%).
// Round 3: grid 2048 was right, but __launch_bounds__(...,8) clamped VGPR to
// 32 -> 300 MB scratch spill -> 300 us. This round: 2048-block grid with
// __launch_bounds__(...,4) (reg cap 128 >> ~60 live, no spill; natural ~60
// VGPR still allows 8 waves/SIMD at runtime) + explicit 1-step B prefetch.
// ---------------------------------------------------------------------------

constexpr int NPTS  = 16384;
constexpr int BLOCK = 256;                        // 4 waves
constexpr int WAVES = BLOCK / 64;

constexpr int ROWS_PER_BLOCK = 256;
constexpr int COLS_PER_BLOCK = 512;
constexpr int NBX = NPTS / ROWS_PER_BLOCK;        // 64
constexpr int NBY = NPTS / COLS_PER_BLOCK;        // 32
constexpr int NBLOCKS = NBX * NBY;                // 2048
constexpr int ROWS_PER_WAVE = ROWS_PER_BLOCK / WAVES;   // 64
constexpr int ATILES = ROWS_PER_WAVE / 32;        // 2
constexpr int CSTEPS = COLS_PER_BLOCK / 64;       // 8 (two 32-col tiles/step)

typedef __attribute__((ext_vector_type(8)))  __bf16 bf16x8;
typedef __attribute__((ext_vector_type(16))) float  f32x16;

__device__ inline unsigned short f2bf(float f) {          // RNE float->bf16
    unsigned u = __float_as_uint(f);
    u += 0x7FFFu + ((u >> 16) & 1u);
    return (unsigned short)(u >> 16);
}
__device__ inline float bf2f(unsigned short h) {
    return __uint_as_float(((unsigned)h) << 16);
}
__device__ inline unsigned pk(unsigned short lo, unsigned short hi) {
    return (unsigned)lo | ((unsigned)hi << 16);
}

// ---------------------------------------------------------------------------
// Pack to FRAG-READY layout: per point two uint4s (one per k-half), each the
// exact 8-bf16 MFMA fragment for that half (verified layout, rounds 1-3):
//   A half0: [phx,phy,phz, plx,ply,plz, phx,phy]
//   A half1: [phz, p2h, p2l, 1, 1, plx, ply, plz]
//   B half0: [mhx,mhy,mhz, mhx,mhy,mhz, mlx,mly]      (m = -2g)
//   B half1: [mlz, 1, 1, g2h, g2l, mlx, mly, mlz]
// Array layout: half-major — Xf[half*NPTS + i].
// ---------------------------------------------------------------------------
__global__ __launch_bounds__(BLOCK) void pack_init_kernel(
    const float* __restrict__ pred, const float* __restrict__ gt,
    uint4* __restrict__ Af, uint4* __restrict__ Bf,
    unsigned int* __restrict__ minP, unsigned int* __restrict__ minG,
    unsigned int* __restrict__ ticket)
{
    const unsigned short ONE = 0x3F80;
    int i = blockIdx.x * BLOCK + threadIdx.x;
    if (i == 0) *ticket = 0u;
    if (i >= NPTS) return;

    {   // A side (pred)
        float x = pred[3*i], y = pred[3*i+1], z = pred[3*i+2];
        unsigned short hx = f2bf(x), hy = f2bf(y), hz = f2bf(z);
        unsigned short lx = f2bf(x - bf2f(hx));
        unsigned short ly = f2bf(y - bf2f(hy));
        unsigned short lz = f2bf(z - bf2f(hz));
        float p2 = fmaf(x, x, fmaf(y, y, z * z));
        unsigned short sh = f2bf(p2), sl = f2bf(p2 - bf2f(sh));
        uint4 h0, h1;
        h0.x = pk(hx, hy); h0.y = pk(hz, lx); h0.z = pk(ly, lz); h0.w = pk(hx, hy);
        h1.x = pk(hz, sh); h1.y = pk(sl, ONE); h1.z = pk(ONE, lx); h1.w = pk(ly, lz);
        Af[i] = h0;
        Af[NPTS + i] = h1;
    }
    {   // B side (gt, pre-scaled by -2)
        float gx = gt[3*i], gy = gt[3*i+1], gz = gt[3*i+2];
        float mx = -2.0f * gx, my = -2.0f * gy, mz = -2.0f * gz;
        unsigned short hx = f2bf(mx), hy = f2bf(my), hz = f2bf(mz);
        unsigned short lx = f2bf(mx - bf2f(hx));
        unsigned short ly = f2bf(my - bf2f(hy));
        unsigned short lz = f2bf(mz - bf2f(hz));
        float g2 = fmaf(gx, gx, fmaf(gy, gy, gz * gz));
        unsigned short sh = f2bf(g2), sl = f2bf(g2 - bf2f(sh));
        uint4 h0, h1;
        h0.x = pk(hx, hy); h0.y = pk(hz, hx); h0.z = pk(hy, hz); h0.w = pk(lx, ly);
        h1.x = pk(lz, ONE); h1.y = pk(ONE, sh); h1.z = pk(sl, lx); h1.w = pk(ly, lz);
        Bf[i] = h0;
        Bf[NPTS + i] = h1;
    }
    minP[i] = 0x7F800000u;   // +inf
    minG[i] = 0x7F800000u;
}

__device__ inline float tree16(const f32x16 a) {   // min of 16 (v_min3 tree)
    float m0 = fminf(fminf(a[0],  a[1]),  a[2]);
    float m1 = fminf(fminf(a[3],  a[4]),  a[5]);
    float m2 = fminf(fminf(a[6],  a[7]),  a[8]);
    float m3 = fminf(fminf(a[9],  a[10]), a[11]);
    float m4 = fminf(fminf(a[12], a[13]), a[14]);
    float m5 = fminf(fminf(m0, m1), m2);
    float m6 = fminf(fminf(m3, m4), a[15]);
    return fminf(m5, m6);
}

// ---------------------------------------------------------------------------
// Main kernel: grid (64,32); block tile 256 rows x 512 cols, 4 waves.
// Wave w owns rows [w*64, w*64+64), one 32-row A-tile at a time.
// C/D layout (HW-verified): col = lane&31, row = (reg&3)+8*(reg>>2)+4*(lane>>5).
// ---------------------------------------------------------------------------
__global__ __launch_bounds__(BLOCK, 4) void chamfer_mfma_kernel(
    const uint4* __restrict__ Af, const uint4* __restrict__ Bf,
    unsigned int* __restrict__ minP, unsigned int* __restrict__ minG,
    const float* __restrict__ wpred, const float* __restrict__ wgt,
    unsigned int* __restrict__ ticket, float* __restrict__ out)
{
    const int tid  = threadIdx.x;
    const int wv   = tid >> 6;
    const int lane = tid & 63;
    const int half = lane >> 5;
    const int ln31 = lane & 31;

    const int rowBase = blockIdx.x * ROWS_PER_BLOCK + wv * ROWS_PER_WAVE;
    const int colBase = blockIdx.y * COLS_PER_BLOCK;

    __shared__ unsigned int cminS[COLS_PER_BLOCK];
    for (int c = tid; c < COLS_PER_BLOCK; c += BLOCK)
        cminS[c] = 0x7F800000u;
    __syncthreads();

    // Per-half base pointers; a fragment is exactly one uint4.
    const uint4* __restrict__ Ah = Af + half * NPTS;
    const uint4* __restrict__ Bh = Bf + half * NPTS + colBase;

    const f32x16 zacc = {0.f,0.f,0.f,0.f, 0.f,0.f,0.f,0.f,
                         0.f,0.f,0.f,0.f, 0.f,0.f,0.f,0.f};

    #pragma unroll 1
    for (int a = 0; a < ATILES; ++a) {
        uint4 ac = Ah[rowBase + a * 32 + ln31];
        bf16x8 af = __builtin_bit_cast(bf16x8, ac);

        float rm[16];
        #pragma unroll
        for (int r = 0; r < 16; ++r) rm[r] = INFINITY;

        // One-step-ahead register prefetch of B fragments.
        uint4 nb0 = Bh[ln31];
        uint4 nb1 = Bh[32 + ln31];

        #pragma unroll
        for (int s = 0; s < CSTEPS; ++s) {
            bf16x8 b0 = __builtin_bit_cast(bf16x8, nb0);
            bf16x8 b1 = __builtin_bit_cast(bf16x8, nb1);
            if (s + 1 < CSTEPS) {
                nb0 = Bh[(s + 1) * 64 + ln31];
                nb1 = Bh[(s + 1) * 64 + 32 + ln31];
            }
            f32x16 acc0 = __builtin_amdgcn_mfma_f32_32x32x16_bf16(af, b0, zacc, 0, 0, 0);
            f32x16 acc1 = __builtin_amdgcn_mfma_f32_32x32x16_bf16(af, b1, zacc, 0, 0, 0);
            #pragma unroll
            for (int r = 0; r < 16; ++r)
                rm[r] = fminf(rm[r], fminf(acc0[r], acc1[r]));   // v_min3
            // Col mins: both halves atomic their own partial (merge in LDS).
            float c0 = fmaxf(tree16(acc0), 0.0f);
            float c1 = fmaxf(tree16(acc1), 0.0f);
            atomicMin(&cminS[s * 64 + ln31],      __float_as_uint(c0));
            atomicMin(&cminS[s * 64 + 32 + ln31], __float_as_uint(c1));
        }

        // Row mins: 4-stage butterfly over 16-lane groups; the two groups
        // (cols 0-15 / 16-31) write the same minP slot -> atomicMin merges.
        #pragma unroll
        for (int s = 1; s < 16; s <<= 1) {
            #pragma unroll
            for (int r = 0; r < 16; ++r)
                rm[r] = fminf(rm[r], __shfl_xor(rm[r], s, 64));
        }
        // Lane q=ln31&15 selects rm[q] via cndmask tree (no runtime indexing).
        const int q  = ln31 & 15;
        const bool b3 = (q & 8) != 0, b2 = (q & 4) != 0,
                   b1 = (q & 2) != 0, b0 = (q & 1) != 0;
        float s0 = b3 ? rm[8]  : rm[0];
        float s1 = b3 ? rm[9]  : rm[1];
        float s2 = b3 ? rm[10] : rm[2];
        float s3 = b3 ? rm[11] : rm[3];
        float s4 = b3 ? rm[12] : rm[4];
        float s5 = b3 ? rm[13] : rm[5];
        float s6 = b3 ? rm[14] : rm[6];
        float s7 = b3 ? rm[15] : rm[7];
        float t0 = b2 ? s4 : s0;
        float t1 = b2 ? s5 : s1;
        float t2 = b2 ? s6 : s2;
        float t3 = b2 ? s7 : s3;
        float u0 = b1 ? t2 : t0;
        float u1 = b1 ? t3 : t1;
        float v  = b0 ? u1 : u0;
        const int rb = rowBase + a * 32 + 4 * half;
        atomicMin(&minP[rb + (q & 3) + 8 * (q >> 2)],
                  __float_as_uint(fmaxf(v, 0.0f)));
    }

    __syncthreads();
    for (int c = tid; c < COLS_PER_BLOCK; c += BLOCK)
        atomicMin(&minG[colBase + c], cminS[c]);   // already clamped >= 0

    // ------------------- ticket: last block finalizes -----------------------
    __shared__ unsigned int sTicket;
    __syncthreads();
    __threadfence();
    if (tid == 0) sTicket = atomicAdd(ticket, 1u);
    __syncthreads();
    if (sTicket != (unsigned)(NBLOCKS - 1)) return;
    __threadfence();

    // Read via identity atomics (coherent across XCDs), weighted sums.
    float np = 0.f, dp = 0.f, ng = 0.f, dg = 0.f;
    for (int i = tid; i < NPTS; i += BLOCK) {
        float v = __uint_as_float(atomicMin(&minP[i], 0xFFFFFFFFu));
        float w = wpred[i];
        np = fmaf(w, v, np); dp += w;
        float u = __uint_as_float(atomicMin(&minG[i], 0xFFFFFFFFu));
        float x = wgt[i];
        ng = fmaf(x, u, ng); dg += x;
    }
    #pragma unroll
    for (int off = 1; off < 64; off <<= 1) {
        np += __shfl_xor(np, off, 64);
        dp += __shfl_xor(dp, off, 64);
        ng += __shfl_xor(ng, off, 64);
        dg += __shfl_xor(dg, off, 64);
    }
    __shared__ float sred[4][WAVES];
    if (lane == 0) { sred[0][wv] = np; sred[1][wv] = dp;
                     sred[2][wv] = ng; sred[3][wv] = dg; }
    __syncthreads();
    if (tid == 0) {
        float NP = 0.f, DP = 0.f, NG = 0.f, DG = 0.f;
        #pragma unroll
        for (int k = 0; k < WAVES; ++k) {
            NP += sred[0][k]; DP += sred[1][k];
            NG += sred[2][k]; DG += sred[3][k];
        }
        out[0] = NP / fmaxf(DP, 1e-9f) + NG / fmaxf(DG, 1e-9f);
    }
}

// ---------------------------------------------------------------------------
extern "C" void kernel_launch(void* const* d_in, const int* in_sizes, int n_in,
                              void* d_out, int out_size, void* d_ws, size_t ws_size,
                              hipStream_t stream)
{
    const float* pred  = (const float*)d_in[0];   // (P,3)
    const float* gt    = (const float*)d_in[1];   // (G,3)
    const float* wpred = (const float*)d_in[2];   // (P,)
    const float* wgt   = (const float*)d_in[3];   // (G,)
    float* out = (float*)d_out;

    // ws: Af(512K) | Bf(512K) | minP(64K) | minG(64K) | ticket  (~1.13 MB)
    uint4* Af = (uint4*)d_ws;
    uint4* Bf = Af + 2 * NPTS;
    unsigned int* minP = (unsigned int*)(Bf + 2 * NPTS);
    unsigned int* minG = minP + NPTS;
    unsigned int* ticket = minG + NPTS;

    pack_init_kernel<<<NPTS / BLOCK, BLOCK, 0, stream>>>(
        pred, gt, Af, Bf, minP, minG, ticket);

    chamfer_mfma_kernel<<<dim3(NBX, NBY), BLOCK, 0, stream>>>(
        Af, Bf, minP, minG, wpred, wgt, ticket, out);
}

// Round 5
// 225.302 us; speedup vs baseline: 1.4843x; 1.1903x over previous
//
#include <hip/hip_runtime.h>
#include <math.h>

// ---------------------------------------------------------------------------
// Chamfer distance via MFMA (gfx950) — round 5.
//
// d2(p,g) = p^2 + g^2 - 2 p.g computed entirely inside
// v_mfma_f32_32x32x16_bf16 via bf16 hi/lo (Dekker) split over K=16 slots
// (HW-verified absmax 0.0, rounds 1-4).
//
// History: r2 = spill-free inner loop (VGPR 60, FETCH 2.5 MB, WRITE 4 MB) but
// only 1024 blocks -> 4 blocks/CU, latency-bound at 123 us. r3/r4 proved the
// 2048-block grid raises occupancy but both perturbed codegen past the 64-VGPR
// tier and spilled (225 MB / 61.5 MB deterministic WRITE_SIZE). This round:
// r2's EXACT kernel body (launch_bounds(...,2), no prefetch, 5-stage butterfly
// + guarded atomics) with only the grid changed to (64,32) = 2048 blocks.
// Tripwire: VGPR must stay ~60 and WRITE_SIZE ~4 MB, else spill returned.
// ---------------------------------------------------------------------------

constexpr int NPTS  = 16384;
constexpr int BLOCK = 256;                        // 4 waves
constexpr int WAVES = BLOCK / 64;

constexpr int ROWS_PER_BLOCK = 256;
constexpr int COLS_PER_BLOCK = 512;
constexpr int NBX = NPTS / ROWS_PER_BLOCK;        // 64
constexpr int NBY = NPTS / COLS_PER_BLOCK;        // 32
constexpr int NBLOCKS = NBX * NBY;                // 2048
constexpr int ROWS_PER_WAVE = ROWS_PER_BLOCK / WAVES;   // 64
constexpr int ATILES = ROWS_PER_WAVE / 32;        // 2
constexpr int CSTEPS = COLS_PER_BLOCK / 64;       // 8 (two 32-col tiles/step)

typedef __attribute__((ext_vector_type(8)))  __bf16 bf16x8;
typedef __attribute__((ext_vector_type(16))) float  f32x16;

__device__ inline unsigned short f2bf(float f) {          // RNE float->bf16
    unsigned u = __float_as_uint(f);
    u += 0x7FFFu + ((u >> 16) & 1u);
    return (unsigned short)(u >> 16);
}
__device__ inline float bf2f(unsigned short h) {
    return __uint_as_float(((unsigned)h) << 16);
}
__device__ inline unsigned pk(unsigned short lo, unsigned short hi) {
    return (unsigned)lo | ((unsigned)hi << 16);
}

// ---------------------------------------------------------------------------
// Pack to FRAG-READY layout: per point two uint4s (one per k-half), each the
// exact 8-bf16 MFMA fragment for that half (verified layout, rounds 1-4):
//   A half0: [phx,phy,phz, plx,ply,plz, phx,phy]
//   A half1: [phz, p2h, p2l, 1, 1, plx, ply, plz]
//   B half0: [mhx,mhy,mhz, mhx,mhy,mhz, mlx,mly]      (m = -2g)
//   B half1: [mlz, 1, 1, g2h, g2l, mlx, mly, mlz]
// Array layout: half-major — Xf[half*NPTS + i].
// ---------------------------------------------------------------------------
__global__ __launch_bounds__(BLOCK) void pack_init_kernel(
    const float* __restrict__ pred, const float* __restrict__ gt,
    uint4* __restrict__ Af, uint4* __restrict__ Bf,
    unsigned int* __restrict__ minP, unsigned int* __restrict__ minG,
    unsigned int* __restrict__ ticket)
{
    const unsigned short ONE = 0x3F80;
    int i = blockIdx.x * BLOCK + threadIdx.x;
    if (i == 0) *ticket = 0u;
    if (i >= NPTS) return;

    {   // A side (pred)
        float x = pred[3*i], y = pred[3*i+1], z = pred[3*i+2];
        unsigned short hx = f2bf(x), hy = f2bf(y), hz = f2bf(z);
        unsigned short lx = f2bf(x - bf2f(hx));
        unsigned short ly = f2bf(y - bf2f(hy));
        unsigned short lz = f2bf(z - bf2f(hz));
        float p2 = fmaf(x, x, fmaf(y, y, z * z));
        unsigned short sh = f2bf(p2), sl = f2bf(p2 - bf2f(sh));
        uint4 h0, h1;
        h0.x = pk(hx, hy); h0.y = pk(hz, lx); h0.z = pk(ly, lz); h0.w = pk(hx, hy);
        h1.x = pk(hz, sh); h1.y = pk(sl, ONE); h1.z = pk(ONE, lx); h1.w = pk(ly, lz);
        Af[i] = h0;
        Af[NPTS + i] = h1;
    }
    {   // B side (gt, pre-scaled by -2)
        float gx = gt[3*i], gy = gt[3*i+1], gz = gt[3*i+2];
        float mx = -2.0f * gx, my = -2.0f * gy, mz = -2.0f * gz;
        unsigned short hx = f2bf(mx), hy = f2bf(my), hz = f2bf(mz);
        unsigned short lx = f2bf(mx - bf2f(hx));
        unsigned short ly = f2bf(my - bf2f(hy));
        unsigned short lz = f2bf(mz - bf2f(hz));
        float g2 = fmaf(gx, gx, fmaf(gy, gy, gz * gz));
        unsigned short sh = f2bf(g2), sl = f2bf(g2 - bf2f(sh));
        uint4 h0, h1;
        h0.x = pk(hx, hy); h0.y = pk(hz, hx); h0.z = pk(hy, hz); h0.w = pk(lx, ly);
        h1.x = pk(lz, ONE); h1.y = pk(ONE, sh); h1.z = pk(sl, lx); h1.w = pk(ly, lz);
        Bf[i] = h0;
        Bf[NPTS + i] = h1;
    }
    minP[i] = 0x7F800000u;   // +inf
    minG[i] = 0x7F800000u;
}

__device__ inline float tree16(const f32x16 a) {   // min of 16 (v_min3 tree)
    float m0 = fminf(fminf(a[0],  a[1]),  a[2]);
    float m1 = fminf(fminf(a[3],  a[4]),  a[5]);
    float m2 = fminf(fminf(a[6],  a[7]),  a[8]);
    float m3 = fminf(fminf(a[9],  a[10]), a[11]);
    float m4 = fminf(fminf(a[12], a[13]), a[14]);
    float m5 = fminf(fminf(m0, m1), m2);
    float m6 = fminf(fminf(m3, m4), a[15]);
    return fminf(m5, m6);
}

// ---------------------------------------------------------------------------
// Main kernel: grid (64,32); block tile 256 rows x 512 cols, 4 waves.
// Wave w owns rows [w*64, w*64+64), one 32-row A-tile at a time.
// C/D layout (HW-verified): col = lane&31, row = (reg&3)+8*(reg>>2)+4*(lane>>5).
// Body is byte-identical to round 2 (the verified spill-free codegen).
// ---------------------------------------------------------------------------
__global__ __launch_bounds__(BLOCK, 2) void chamfer_mfma_kernel(
    const uint4* __restrict__ Af, const uint4* __restrict__ Bf,
    unsigned int* __restrict__ minP, unsigned int* __restrict__ minG,
    const float* __restrict__ wpred, const float* __restrict__ wgt,
    unsigned int* __restrict__ ticket, float* __restrict__ out)
{
    const int tid  = threadIdx.x;
    const int wv   = tid >> 6;
    const int lane = tid & 63;
    const int half = lane >> 5;
    const int ln31 = lane & 31;

    const int rowBase = blockIdx.x * ROWS_PER_BLOCK + wv * ROWS_PER_WAVE;
    const int colBase = blockIdx.y * COLS_PER_BLOCK;

    __shared__ unsigned int cminS[COLS_PER_BLOCK];
    for (int c = tid; c < COLS_PER_BLOCK; c += BLOCK)
        cminS[c] = 0x7F800000u;
    __syncthreads();

    // Per-half base pointers; a fragment is exactly one uint4.
    const uint4* __restrict__ Ah = Af + half * NPTS;
    const uint4* __restrict__ Bh = Bf + half * NPTS + colBase;

    const f32x16 zacc = {0.f,0.f,0.f,0.f, 0.f,0.f,0.f,0.f,
                         0.f,0.f,0.f,0.f, 0.f,0.f,0.f,0.f};

    #pragma unroll 1
    for (int a = 0; a < ATILES; ++a) {
        uint4 ac = Ah[rowBase + a * 32 + ln31];
        bf16x8 af = __builtin_bit_cast(bf16x8, ac);

        float rm[16];
        #pragma unroll
        for (int r = 0; r < 16; ++r) rm[r] = INFINITY;

        #pragma unroll 2
        for (int s = 0; s < CSTEPS; ++s) {
            bf16x8 b0 = __builtin_bit_cast(bf16x8, Bh[s * 64 + ln31]);
            bf16x8 b1 = __builtin_bit_cast(bf16x8, Bh[s * 64 + 32 + ln31]);
            f32x16 acc0 = __builtin_amdgcn_mfma_f32_32x32x16_bf16(af, b0, zacc, 0, 0, 0);
            f32x16 acc1 = __builtin_amdgcn_mfma_f32_32x32x16_bf16(af, b1, zacc, 0, 0, 0);
            #pragma unroll
            for (int r = 0; r < 16; ++r)
                rm[r] = fminf(rm[r], fminf(acc0[r], acc1[r]));   // v_min3
            // Column mins for this A-tile: tree over 16 rows, combine halves.
            float c0 = fmaxf(tree16(acc0), 0.0f);
            float c1 = fmaxf(tree16(acc1), 0.0f);
            c0 = fminf(c0, __shfl_xor(c0, 32, 64));
            c1 = fminf(c1, __shfl_xor(c1, 32, 64));
            if (half == 0) {
                atomicMin(&cminS[s * 64 + ln31],      __float_as_uint(c0));
                atomicMin(&cminS[s * 64 + 32 + ln31], __float_as_uint(c1));
            }
        }

        // Row mins: butterfly over the 32 col-lanes.
        #pragma unroll
        for (int s = 1; s < 32; s <<= 1) {
            #pragma unroll
            for (int r = 0; r < 16; ++r)
                rm[r] = fminf(rm[r], __shfl_xor(rm[r], s, 64));
        }
        const int rb = rowBase + a * 32 + 4 * half;
        #pragma unroll
        for (int r = 0; r < 16; ++r) {
            if (ln31 == r)
                atomicMin(&minP[rb + (r & 3) + 8 * (r >> 2)],
                          __float_as_uint(fmaxf(rm[r], 0.0f)));
        }
    }

    __syncthreads();
    for (int c = tid; c < COLS_PER_BLOCK; c += BLOCK)
        atomicMin(&minG[colBase + c], cminS[c]);   // already clamped >= 0

    // ------------------- ticket: last block finalizes -----------------------
    __shared__ unsigned int sTicket;
    __syncthreads();
    __threadfence();
    if (tid == 0) sTicket = atomicAdd(ticket, 1u);
    __syncthreads();
    if (sTicket != (unsigned)(NBLOCKS - 1)) return;
    __threadfence();

    // Read via identity atomics (coherent across XCDs), weighted sums.
    float np = 0.f, dp = 0.f, ng = 0.f, dg = 0.f;
    for (int i = tid; i < NPTS; i += BLOCK) {
        float v = __uint_as_float(atomicMin(&minP[i], 0xFFFFFFFFu));
        float w = wpred[i];
        np = fmaf(w, v, np); dp += w;
        float u = __uint_as_float(atomicMin(&minG[i], 0xFFFFFFFFu));
        float x = wgt[i];
        ng = fmaf(x, u, ng); dg += x;
    }
    #pragma unroll
    for (int off = 1; off < 64; off <<= 1) {
        np += __shfl_xor(np, off, 64);
        dp += __shfl_xor(dp, off, 64);
        ng += __shfl_xor(ng, off, 64);
        dg += __shfl_xor(dg, off, 64);
    }
    __shared__ float sred[4][WAVES];
    if (lane == 0) { sred[0][wv] = np; sred[1][wv] = dp;
                     sred[2][wv] = ng; sred[3][wv] = dg; }
    __syncthreads();
    if (tid == 0) {
        float NP = 0.f, DP = 0.f, NG = 0.f, DG = 0.f;
        #pragma unroll
        for (int k = 0; k < WAVES; ++k) {
            NP += sred[0][k]; DP += sred[1][k];
            NG += sred[2][k]; DG += sred[3][k];
        }
        out[0] = NP / fmaxf(DP, 1e-9f) + NG / fmaxf(DG, 1e-9f);
    }
}

// ---------------------------------------------------------------------------
extern "C" void kernel_launch(void* const* d_in, const int* in_sizes, int n_in,
                              void* d_out, int out_size, void* d_ws, size_t ws_size,
                              hipStream_t stream)
{
    const float* pred  = (const float*)d_in[0];   // (P,3)
    const float* gt    = (const float*)d_in[1];   // (G,3)
    const float* wpred = (const float*)d_in[2];   // (P,)
    const float* wgt   = (const float*)d_in[3];   // (G,)
    float* out = (float*)d_out;

    // ws: Af(512K) | Bf(512K) | minP(64K) | minG(64K) | ticket  (~1.13 MB)
    uint4* Af = (uint4*)d_ws;
    uint4* Bf = Af + 2 * NPTS;
    unsigned int* minP = (unsigned int*)(Bf + 2 * NPTS);
    unsigned int* minG = minP + NPTS;
    unsigned int* ticket = minG + NPTS;

    pack_init_kernel<<<NPTS / BLOCK, BLOCK, 0, stream>>>(
        pred, gt, Af, Bf, minP, minG, ticket);

    chamfer_mfma_kernel<<<dim3(NBX, NBY), BLOCK, 0, stream>>>(
        Af, Bf, minP, minG, wpred, wgt, ticket, out);
}